// Round 1
// baseline (288.156 us; speedup 1.0000x reference)
//
#include <hip/hip_runtime.h>

#define DIM 256
#define NH 8
#define HE 32          // head dim E
#define BALL 16        // ball size M
#define NBALLS 512
#define NM 8192
#define QB 32          // queries per block in sim/topk kernel

// ---------------------------------------------------------------------------
// K1: x' = x + rel @ W_pe^T + b_pe, rel = pos - per-ball mean(pos)
// one block per ball, 256 threads (one per feature dim)
// ---------------------------------------------------------------------------
__global__ __launch_bounds__(256) void k_posembed(
    const float* __restrict__ x, const float* __restrict__ pos,
    const float* __restrict__ Wpe, const float* __restrict__ bpe,
    float* __restrict__ xp) {
  __shared__ float ps[BALL * 3];
  __shared__ float mean_s[3];
  int ball = blockIdx.x;
  int tid = threadIdx.x;
  if (tid < BALL * 3) ps[tid] = pos[ball * BALL * 3 + tid];
  __syncthreads();
  if (tid < 3) {
    float s = 0.f;
    for (int m = 0; m < BALL; ++m) s += ps[m * 3 + tid];
    mean_s[tid] = s * (1.f / BALL);
  }
  __syncthreads();
  int d = tid;
  float w0 = Wpe[d * 3 + 0], w1 = Wpe[d * 3 + 1], w2 = Wpe[d * 3 + 2];
  float bp = bpe[d];
  float m0 = mean_s[0], m1 = mean_s[1], m2 = mean_s[2];
  for (int m = 0; m < BALL; ++m) {
    int t = ball * BALL + m;
    float r0 = ps[m * 3 + 0] - m0;
    float r1 = ps[m * 3 + 1] - m1;
    float r2 = ps[m * 3 + 2] - m2;
    xp[t * DIM + d] = x[t * DIM + d] + r0 * w0 + r1 * w1 + r2 * w2 + bp;
  }
}

// ---------------------------------------------------------------------------
// Shared fp32 tiled GEMM config: C[M,N] = A[M,K] * B[N,K]^T (+bias)
// BM=BN=64, BK=16, 256 threads, 4x4 microtile
// ---------------------------------------------------------------------------
#define BM 64
#define BN 64
#define BK 16
#define LDP 68  // padded leading dim: 2-way LDS aliasing max (free on CDNA4)

// K2: qkv = x' @ W_qkv^T + b_qkv, scattered to q/k/v buffers.
// output column o = h*96 + e*3 + c (c: 0=q,1=k,2=v), dest layout [H][nm][E]
__global__ __launch_bounds__(256) void k_qkv_gemm(
    const float* __restrict__ A, const float* __restrict__ B,
    const float* __restrict__ bias,
    float* __restrict__ qbuf, float* __restrict__ kbuf,
    float* __restrict__ vbuf) {
  __shared__ float As[BK][LDP];
  __shared__ float Bs[BK][LDP];
  int tid = threadIdx.x;
  int m0 = blockIdx.x * BM;
  int n0 = blockIdx.y * BN;
  int lr = tid >> 2;        // 0..63
  int lk = (tid & 3) * 4;   // 0,4,8,12
  int tx = tid & 15, ty = tid >> 4;
  float acc[4][4] = {};
  for (int k0 = 0; k0 < DIM; k0 += BK) {
    float4 av = *(const float4*)&A[(m0 + lr) * DIM + k0 + lk];
    float4 bv = *(const float4*)&B[(n0 + lr) * DIM + k0 + lk];
    As[lk + 0][lr] = av.x; As[lk + 1][lr] = av.y;
    As[lk + 2][lr] = av.z; As[lk + 3][lr] = av.w;
    Bs[lk + 0][lr] = bv.x; Bs[lk + 1][lr] = bv.y;
    Bs[lk + 2][lr] = bv.z; Bs[lk + 3][lr] = bv.w;
    __syncthreads();
#pragma unroll
    for (int k = 0; k < BK; ++k) {
      float4 a = *(const float4*)&As[k][ty * 4];
      float4 b = *(const float4*)&Bs[k][tx * 4];
      float ar[4] = {a.x, a.y, a.z, a.w};
      float br[4] = {b.x, b.y, b.z, b.w};
#pragma unroll
      for (int i = 0; i < 4; ++i)
#pragma unroll
        for (int j = 0; j < 4; ++j) acc[i][j] += ar[i] * br[j];
    }
    __syncthreads();
  }
#pragma unroll
  for (int i = 0; i < 4; ++i) {
    int t = m0 + ty * 4 + i;
#pragma unroll
    for (int j = 0; j < 4; ++j) {
      int o = n0 + tx * 4 + j;
      float val = acc[i][j] + bias[o];
      int c = o % 3;
      int r = o / 3;          // h*32 + e
      int e = r & 31, h = r >> 5;
      float* dst = (c == 0) ? qbuf : (c == 1) ? kbuf : vbuf;
      dst[(h * NM + t) * HE + e] = val;
    }
  }
}

// K2b: kmean[h][ball][e] = mean over m of kbuf[h][ball*16+m][e]
__global__ __launch_bounds__(256) void k_kmean(
    const float* __restrict__ kbuf, float* __restrict__ kmean) {
  int tid = threadIdx.x;
  int gb = blockIdx.x * 8 + (tid >> 5);  // h*512 + ball
  int e = tid & 31;
  int h = gb >> 9, ball = gb & 511;
  float s = 0.f;
#pragma unroll
  for (int m = 0; m < BALL; ++m)
    s += kbuf[(h * NM + ball * BALL + m) * HE + e];
  kmean[gb * HE + e] = s * (1.f / BALL);
}

// ---------------------------------------------------------------------------
// K3: sim = q . kmean over all 512 balls, keep top-2 ball ids per (h,q).
// Block: 256 threads, each owns 2 balls (kmean rows in registers),
// processes QB=32 queries; top-2 via wave butterfly + LDS cross-wave merge.
// ---------------------------------------------------------------------------
__device__ __forceinline__ void merge_top2(float& v0, int& i0, float& v1,
                                           int& i1, float w0, int j0,
                                           float w1, int j1) {
  if (w0 > v0) {
    float tv; int ti;
    tv = v0; v0 = w0; w0 = tv; ti = i0; i0 = j0; j0 = ti;
    tv = v1; v1 = w1; w1 = tv; ti = i1; i1 = j1; j1 = ti;
  }
  if (w0 > v1) { v1 = w0; i1 = j0; }
}

__global__ __launch_bounds__(256) void k_sim_topk(
    const float* __restrict__ qbuf, const float* __restrict__ kmean,
    int* __restrict__ topk) {
  __shared__ float q_s[QB][HE];
  __shared__ float candv[QB][4][2];
  __shared__ int candi[QB][4][2];
  int tid = threadIdx.x;
  int h = blockIdx.y;
  int t0 = blockIdx.x * QB;
#pragma unroll
  for (int i = 0; i < (QB * HE) / 256; ++i) {
    int p = tid + 256 * i;
    q_s[p >> 5][p & 31] = qbuf[(h * NM + t0 + (p >> 5)) * HE + (p & 31)];
  }
  float km0[HE], km1[HE];
  {
    const float4* k0 = (const float4*)&kmean[(h * NBALLS + 2 * tid) * HE];
    const float4* k1 = (const float4*)&kmean[(h * NBALLS + 2 * tid + 1) * HE];
#pragma unroll
    for (int u = 0; u < 8; ++u) {
      float4 a = k0[u], b = k1[u];
      km0[4 * u + 0] = a.x; km0[4 * u + 1] = a.y;
      km0[4 * u + 2] = a.z; km0[4 * u + 3] = a.w;
      km1[4 * u + 0] = b.x; km1[4 * u + 1] = b.y;
      km1[4 * u + 2] = b.z; km1[4 * u + 3] = b.w;
    }
  }
  __syncthreads();
  int lane = tid & 63, wid = tid >> 6;
  for (int qi = 0; qi < QB; ++qi) {
    float s0 = 0.f, s1 = 0.f;
#pragma unroll
    for (int e = 0; e < HE; ++e) {
      float qe = q_s[qi][e];
      s0 += qe * km0[e];
      s1 += qe * km1[e];
    }
    float v0 = s0, v1 = s1;
    int i0 = 2 * tid, i1 = 2 * tid + 1;
    if (s1 > s0) { v0 = s1; i0 = 2 * tid + 1; v1 = s0; i1 = 2 * tid; }
#pragma unroll
    for (int off = 1; off < 64; off <<= 1) {
      float w0 = __shfl_xor(v0, off), w1 = __shfl_xor(v1, off);
      int j0 = __shfl_xor(i0, off), j1 = __shfl_xor(i1, off);
      merge_top2(v0, i0, v1, i1, w0, j0, w1, j1);
    }
    if (lane == 0) {
      candv[qi][wid][0] = v0; candv[qi][wid][1] = v1;
      candi[qi][wid][0] = i0; candi[qi][wid][1] = i1;
    }
  }
  __syncthreads();
  if (tid < QB) {
    float v0 = candv[tid][0][0], v1 = candv[tid][0][1];
    int i0 = candi[tid][0][0], i1 = candi[tid][0][1];
#pragma unroll
    for (int w = 1; w < 4; ++w) {
      merge_top2(v0, i0, v1, i1, candv[tid][w][0], candi[tid][w][0],
                 candv[tid][w][1], candi[tid][w][1]);
    }
    topk[(h * NM + t0 + tid) * 2 + 0] = i0;
    topk[(h * NM + t0 + tid) * 2 + 1] = i1;
  }
}

// ---------------------------------------------------------------------------
// K4: gather 2 balls' K/V, logits, softmax, weighted-V. One wave per (h,q).
// ---------------------------------------------------------------------------
__global__ __launch_bounds__(64) void k_attn(
    const float* __restrict__ qbuf, const float* __restrict__ kbuf,
    const float* __restrict__ vbuf, const int* __restrict__ topk,
    float* __restrict__ attout) {
  __shared__ float q_s[HE];
  __shared__ float ks[32 * 33];
  __shared__ float vs[32 * 33];
  __shared__ float attw[32];
  int pair = blockIdx.x;
  int h = pair >> 13, t = pair & (NM - 1);
  int tid = threadIdx.x;
  int b0 = topk[(h * NM + t) * 2 + 0];
  int b1 = topk[(h * NM + t) * 2 + 1];
  if (tid < HE) q_s[tid] = qbuf[(h * NM + t) * HE + tid];
#pragma unroll
  for (int i = 0; i < 16; ++i) {
    int p = tid + 64 * i;  // 0..1023
    int j = p >> 5, e = p & 31;
    int ball = (j < 16) ? b0 : b1;
    int m = j & 15;
    int src = (h * NM + ball * BALL + m) * HE + e;
    ks[j * 33 + e] = kbuf[src];
    vs[j * 33 + e] = vbuf[src];
  }
  __syncthreads();
  int j = tid & 31, half = tid >> 5;
  int e0 = half * 16;
  float partial = 0.f;
#pragma unroll
  for (int e = 0; e < 16; ++e) partial += q_s[e0 + e] * ks[j * 33 + e0 + e];
  partial += __shfl_xor(partial, 32);
  float logit = partial * 0.17677669529663687f;  // 1/sqrt(32)
  float mx = logit;
#pragma unroll
  for (int mk = 1; mk <= 16; mk <<= 1) mx = fmaxf(mx, __shfl_xor(mx, mk));
  float pexp = __expf(logit - mx);
  float sum = pexp;
#pragma unroll
  for (int mk = 1; mk <= 16; mk <<= 1) sum += __shfl_xor(sum, mk);
  float attn = pexp / sum;
  if (tid < 32) attw[j] = attn;
  __syncthreads();
  int e = tid & 31, j0 = half * 16;
  float po = 0.f;
#pragma unroll
  for (int jj = 0; jj < 16; ++jj) po += attw[j0 + jj] * vs[(j0 + jj) * 33 + e];
  po += __shfl_xor(po, 32);
  if (tid < 32) attout[t * DIM + h * HE + e] = po;
}

// K5: out = attout @ W_proj^T + b_proj  (same tiling as K2, dense output)
__global__ __launch_bounds__(256) void k_proj(
    const float* __restrict__ A, const float* __restrict__ B,
    const float* __restrict__ bias, float* __restrict__ out) {
  __shared__ float As[BK][LDP];
  __shared__ float Bs[BK][LDP];
  int tid = threadIdx.x;
  int m0 = blockIdx.x * BM;
  int n0 = blockIdx.y * BN;
  int lr = tid >> 2;
  int lk = (tid & 3) * 4;
  int tx = tid & 15, ty = tid >> 4;
  float acc[4][4] = {};
  for (int k0 = 0; k0 < DIM; k0 += BK) {
    float4 av = *(const float4*)&A[(m0 + lr) * DIM + k0 + lk];
    float4 bv = *(const float4*)&B[(n0 + lr) * DIM + k0 + lk];
    As[lk + 0][lr] = av.x; As[lk + 1][lr] = av.y;
    As[lk + 2][lr] = av.z; As[lk + 3][lr] = av.w;
    Bs[lk + 0][lr] = bv.x; Bs[lk + 1][lr] = bv.y;
    Bs[lk + 2][lr] = bv.z; Bs[lk + 3][lr] = bv.w;
    __syncthreads();
#pragma unroll
    for (int k = 0; k < BK; ++k) {
      float4 a = *(const float4*)&As[k][ty * 4];
      float4 b = *(const float4*)&Bs[k][tx * 4];
      float ar[4] = {a.x, a.y, a.z, a.w};
      float br[4] = {b.x, b.y, b.z, b.w};
#pragma unroll
      for (int i = 0; i < 4; ++i)
#pragma unroll
        for (int j = 0; j < 4; ++j) acc[i][j] += ar[i] * br[j];
    }
    __syncthreads();
  }
#pragma unroll
  for (int i = 0; i < 4; ++i) {
    int t = m0 + ty * 4 + i;
#pragma unroll
    for (int j = 0; j < 4; ++j) {
      int o = n0 + tx * 4 + j;
      out[t * DIM + o] = acc[i][j] + bias[o];
    }
  }
}

extern "C" void kernel_launch(void* const* d_in, const int* in_sizes, int n_in,
                              void* d_out, int out_size, void* d_ws,
                              size_t ws_size, hipStream_t stream) {
  const float* x = (const float*)d_in[0];
  const float* pos = (const float*)d_in[1];
  const float* Wqkv = (const float*)d_in[2];
  const float* bqkv = (const float*)d_in[3];
  const float* Wpe = (const float*)d_in[4];
  const float* bpe = (const float*)d_in[5];
  const float* Wproj = (const float*)d_in[6];
  const float* bproj = (const float*)d_in[7];
  float* out = (float*)d_out;

  float* ws = (float*)d_ws;
  float* xp = ws;                          // NM*DIM
  float* qbuf = xp + NM * DIM;             // NH*NM*HE
  float* kbuf = qbuf + NH * NM * HE;       // NH*NM*HE
  float* vbuf = kbuf + NH * NM * HE;       // NH*NM*HE
  float* kmean = vbuf + NH * NM * HE;      // NH*NBALLS*HE
  int* topk = (int*)(kmean + NH * NBALLS * HE);  // NH*NM*2 ints
  float* attout = (float*)(topk + NH * NM * 2);  // NM*DIM
  // total ~41 MB of d_ws

  k_posembed<<<NBALLS, 256, 0, stream>>>(x, pos, Wpe, bpe, xp);
  k_qkv_gemm<<<dim3(NM / BM, 768 / BN), 256, 0, stream>>>(xp, Wqkv, bqkv,
                                                          qbuf, kbuf, vbuf);
  k_kmean<<<(NH * NBALLS) / 8, 256, 0, stream>>>(kbuf, kmean);
  k_sim_topk<<<dim3(NM / QB, NH), 256, 0, stream>>>(qbuf, kmean, topk);
  k_attn<<<NH * NM, 64, 0, stream>>>(qbuf, kbuf, vbuf, topk, attout);
  k_proj<<<dim3(NM / BM, DIM / BN), 256, 0, stream>>>(attout, Wproj, bproj,
                                                      out);
}